// Round 4
// baseline (590.194 us; speedup 1.0000x reference)
//
#include <hip/hip_runtime.h>
#include <hip/hip_bf16.h>

// GCN over Block-CSR adjacency. ALL I/O BUFFERS ARE FLOAT32 (reference dtypes).
// Compute: bf16 MFMA, fp32 accumulate; intermediates stored bf16.
//
// Round 10: fused_v2 — batched rows, one barrier, wave-owned LayerNorm.
// Evidence R9: all fused dispatches ~136us regardless of gather bytes (L0's
// working set is L3-resident!) => effective-BW-bound at 2.65 TB/s; per-row time
// == 35KB / (BW/CU). R6's 3.8 TB/s came from continuous, loosely-synced issue;
// R9's per-row barriers made issue bursty. Also 4.2M bank-conflict cycles from
// scalar bf16 S-writes. Fix, keeping the fusion byte win:
//  - pass1: 8 rows per WG streamed with 2-row lookahead (gemm_bt's proven aw[2]
//    idiom), NO barriers. Swapped-operand MFMA (mfma(X^T, A^T) -> S^T) makes
//    each lane hold 4 consecutive-f values => b64 vectorized S-writes to LDS
//    (bank conflicts gone). Single bf16 S plane (== old zbt rounding count).
//  - ONE __syncthreads per WG (16x fewer barriers than R9).
//  - pass2: wave w owns row-block w fully: dense S@W (W^T streamed 16B frags
//    from L2-resident bf16 scratch), bias+relu+LN entirely in-wave via shfl.
//    h stored as b64 frags in the [F][16] gather layout.
//  - weights: w0t/w1t bf16 in d_out scratch (d_out untouched until out-layer);
//    out-layer reads W2 from the f32 input directly (no scratch race).
//
// ws: fbt [0,32MiB) dead after L0; hB [0,64); hA [64,128). 128 MiB exact.

typedef __bf16 bf16;
typedef bf16 bf16x8 __attribute__((ext_vector_type(8)));
typedef bf16 bf16x4 __attribute__((ext_vector_type(4)));
typedef float f32x4 __attribute__((ext_vector_type(4)));

#define N_NODES 131072
#define BRQ 8192      // block rows (= N/16)
#define KNZ 8         // nonzero blocks per block row
#define IN_F 128
#define HID 256
#define NCLS 64

static __device__ __forceinline__ f32x4 mfma16(bf16x8 a, bf16x8 b, f32x4 c) {
  return __builtin_amdgcn_mfma_f32_16x16x32_bf16(a, b, c, 0, 0, 0);
}

static __device__ __forceinline__ bf16x8 cvt8(f32x4 a0, f32x4 a1) {
  bf16x8 r;
  r[0] = (bf16)a0[0]; r[1] = (bf16)a0[1]; r[2] = (bf16)a0[2]; r[3] = (bf16)a0[3];
  r[4] = (bf16)a1[0]; r[5] = (bf16)a1[1]; r[6] = (bf16)a1[2]; r[7] = (bf16)a1[3];
  return r;
}

// ---------------- W0, W1 -> transposed bf16 [F_OUT][F_IN] in d_out scratch ------
__global__ __launch_bounds__(256) void transpose_all(const float* __restrict__ W0,
                                                     const float* __restrict__ W1,
                                                     bf16* __restrict__ w0t,
                                                     bf16* __restrict__ w1t) {
  int idx = blockIdx.x * 256 + threadIdx.x;
  if (idx < 32768) {
    int r = idx >> 8, c = idx & 255;                   // W0: 128 x 256
    w0t[c * 128 + r] = (bf16)W0[idx];
  } else {
    int j = idx - 32768; int r = j >> 8, c = j & 255;  // W1: 256 x 256
    w1t[c * 256 + r] = (bf16)W1[j];
  }
}

// ---------------- features -> blocked-transposed bf16 [BRQ][128][16] -------------
__global__ __launch_bounds__(256) void prep_fbt(const float* __restrict__ F,
                                                bf16* __restrict__ out) {
  __shared__ float T[16][132];
  const int b = blockIdx.x, tid = threadIdx.x;
#pragma unroll
  for (int p = 0; p < 2; ++p) {
    int ci = tid + p * 256;            // f32x4 chunk id (512 total)
    int r = ci >> 5, c4 = ci & 31;
    f32x4 v = *(const f32x4*)(F + ((long)b * 16 + r) * 128 + c4 * 4);
    *(f32x4*)&T[r][c4 * 4] = v;
  }
  __syncthreads();
  int f = tid >> 1, r0 = (tid & 1) * 8;
  bf16x8 o;
#pragma unroll
  for (int e = 0; e < 8; ++e) o[e] = (bf16)T[r0 + e][f];
  *(bf16x8*)(out + (long)b * 2048 + f * 16 + r0) = o;
}

// ---------------- fused (A @ X) @ W [+bias +relu +LN] ----------------------------
// 8 waves, 8 block-rows per WG. pass1: waves slice f, stream gathers (2-row
// lookahead), swapped MFMA -> S^T, b64 writes to LDS. One barrier. pass2:
// wave w owns row-block w: dense + (LN | bias-only f32 out), all in-wave.
template<int F_IN, int F_OUT, bool IS_OUT>
__global__ __launch_bounds__(512, 2) void fused_v2(
    const float* __restrict__ Abv, const int* __restrict__ Abc,
    const bf16* __restrict__ Xbt, const bf16* __restrict__ WT,
    const float* __restrict__ W2, const float* __restrict__ bias,
    const float* __restrict__ gamma, const float* __restrict__ beta,
    bf16* __restrict__ Hbt, float* __restrict__ Out) {
  constexpr int TS = F_IN / 128;            // spmm f-chunks per wave
  constexpr int KD = F_IN / 32;             // dense k-steps
  constexpr int T2 = F_OUT / 16;            // dense n-chunks (per wave, full row)
  constexpr int RW = F_IN + 8;              // S row stride (bank-spread pad)
  constexpr long XBLK = (long)F_IN * 32;    // gathered block bytes

  const int wave = threadIdx.x >> 6;
  const int lane = threadIdx.x & 63;
  const int l15 = lane & 15, q = lane >> 4;
  const int cst = (q & 1) * 8, half = q >> 1;
  const int fsl = wave * 16 * TS;

  __shared__ bf16 Sar[8 * 16 * RW];         // S for 8 row-blocks

  const int b0 = blockIdx.x * 8;
  const char* zb = (const char*)Xbt;
  const unsigned fo0 = (unsigned)((fsl + l15) * 32 + cst * 2);

  // ---------------- pass 1: S[rb] = A_rb @ X  (all 8 rows) ----------------
  int bca[8][4];
#pragma unroll
  for (int rr = 0; rr < 8; ++rr)
#pragma unroll
    for (int kp = 0; kp < 4; ++kp)
      bca[rr][kp] = Abc[(b0 + rr) * KNZ + 2 * kp + half];

  bf16x8 bfr[2][4][TS];
  f32x4  ar[2][4][2];

  auto issue = [&](int rr, int slot) {
    const float* ab = Abv + (long)(b0 + rr) * (KNZ * 256) + l15 * 16 + cst;
#pragma unroll
    for (int kp = 0; kp < 4; ++kp) {
      const char* src = zb + (long)bca[rr][kp] * XBLK + fo0;
#pragma unroll
      for (int t = 0; t < TS; ++t)
        bfr[slot][kp][t] = *(const bf16x8*)(src + (unsigned)t * 512);
      const float* p = ab + (2 * kp + half) * 256;
      ar[slot][kp][0] = *(const f32x4*)p;
      ar[slot][kp][1] = *(const f32x4*)(p + 4);
    }
  };
  issue(0, 0);
  issue(1, 1);

#pragma unroll
  for (int r = 0; r < 8; ++r) {
    const int slot = r & 1;
    bf16x8 afr[4];
#pragma unroll
    for (int kp = 0; kp < 4; ++kp) afr[kp] = cvt8(ar[slot][kp][0], ar[slot][kp][1]);
    f32x4 sacc[TS] = {};
#pragma unroll
    for (int kp = 0; kp < 4; ++kp)
#pragma unroll
      for (int t = 0; t < TS; ++t)
        sacc[t] = mfma16(bfr[slot][kp][t], afr[kp], sacc[t]);  // swapped -> S^T
    // lane (q,l15) holds S[r=l15][f = fsl+16t+4q+i] -> b64 vectorized write
#pragma unroll
    for (int t = 0; t < TS; ++t) {
      bf16x4 sv;
#pragma unroll
      for (int i = 0; i < 4; ++i) sv[i] = (bf16)sacc[t][i];
      *(bf16x4*)&Sar[(r * 16 + l15) * RW + fsl + 16 * t + 4 * q] = sv;
    }
    if (r + 2 < 8) issue(r + 2, slot);
  }

  __syncthreads();   // the only barrier; no vm loads outstanding here

  // ---------------- pass 2: wave w owns row-block rb = w ----------------
  const int rb = wave;

  if constexpr (!IS_OUT) {
    float bv[T2], gv[T2], btv[T2];
#pragma unroll
    for (int t = 0; t < T2; ++t) {
      int n = 16 * t + l15;
      bv[t] = bias[n]; gv[t] = gamma[n]; btv[t] = beta[n];
    }
    f32x4 dacc[T2] = {};
#pragma unroll
    for (int kp = 0; kp < KD; ++kp) {
      bf16x8 sa = *(const bf16x8*)&Sar[(rb * 16 + l15) * RW + 32 * kp + 8 * q];
      const bf16* wb = WT + 32 * kp + 8 * q + (long)l15 * F_IN;
#pragma unroll
      for (int t = 0; t < T2; ++t) {
        bf16x8 wf = *(const bf16x8*)(wb + (long)(16 * t) * F_IN);
        dacc[t] = mfma16(sa, wf, dacc[t]);
      }
    }
    // bias + relu + LayerNorm, fully in-wave (rows 4q+i, sum over t and l15)
    float ps[4] = {0.f, 0.f, 0.f, 0.f}, pss[4] = {0.f, 0.f, 0.f, 0.f};
#pragma unroll
    for (int t = 0; t < T2; ++t)
#pragma unroll
      for (int i = 0; i < 4; ++i) {
        float v = dacc[t][i] + bv[t];
        v = v > 0.f ? v : 0.f;
        dacc[t][i] = v;
        ps[i] += v;
        pss[i] += v * v;
      }
#pragma unroll
    for (int m = 1; m < 16; m <<= 1)
#pragma unroll
      for (int i = 0; i < 4; ++i) {
        ps[i]  += __shfl_xor(ps[i], m, 64);
        pss[i] += __shfl_xor(pss[i], m, 64);
      }
    float mu[4], rstd[4];
#pragma unroll
    for (int i = 0; i < 4; ++i) {
      mu[i] = ps[i] * (1.f / F_OUT);
      float var = pss[i] * (1.f / F_OUT) - mu[i] * mu[i];
      rstd[i] = rsqrtf(var + 1e-5f);
    }
    bf16* hb = Hbt + (long)(b0 + rb) * (F_OUT * 16);
#pragma unroll
    for (int t = 0; t < T2; ++t) {
      bf16x4 o;
#pragma unroll
      for (int i = 0; i < 4; ++i)
        o[i] = (bf16)((dacc[t][i] - mu[i]) * rstd[i] * gv[t] + btv[t]);
      *(bf16x4*)(hb + (16 * t + l15) * 16 + 4 * q) = o;
    }
  } else {
    // output layer: W2 f32 [F_IN][64] strided preload -> bf16 frags; f32 out
    bf16x8 wf2[KD][T2];
#pragma unroll
    for (int kp = 0; kp < KD; ++kp)
#pragma unroll
      for (int t = 0; t < T2; ++t) {
        const float* wp = W2 + (long)(32 * kp + 8 * q) * F_OUT + 16 * t + l15;
        bf16x8 v;
#pragma unroll
        for (int j = 0; j < 8; ++j) v[j] = (bf16)wp[(long)j * F_OUT];
        wf2[kp][t] = v;
      }
    float bv[T2];
#pragma unroll
    for (int t = 0; t < T2; ++t) bv[t] = bias[16 * t + l15];
    f32x4 dacc[T2] = {};
#pragma unroll
    for (int kp = 0; kp < KD; ++kp) {
      bf16x8 sa = *(const bf16x8*)&Sar[(rb * 16 + l15) * RW + 32 * kp + 8 * q];
#pragma unroll
      for (int t = 0; t < T2; ++t)
        dacc[t] = mfma16(sa, wf2[kp][t], dacc[t]);
    }
#pragma unroll
    for (int t = 0; t < T2; ++t) {
      int n = 16 * t + l15;
#pragma unroll
      for (int i = 0; i < 4; ++i)
        Out[((long)(b0 + rb) * 16 + 4 * q + i) * NCLS + n] = dacc[t][i] + bv[t];
    }
  }
}

extern "C" void kernel_launch(void* const* d_in, const int* in_sizes, int n_in,
                              void* d_out, int out_size, void* d_ws, size_t ws_size,
                              hipStream_t stream) {
  const float* features = (const float*)d_in[0];
  const float* bvals    = (const float*)d_in[1];
  const float* W0       = (const float*)d_in[2];
  const float* b0v      = (const float*)d_in[3];
  const float* W1       = (const float*)d_in[4];
  const float* b1v      = (const float*)d_in[5];
  const float* W2       = (const float*)d_in[6];
  const float* b2v      = (const float*)d_in[7];
  const float* g0       = (const float*)d_in[8];
  const float* beta0    = (const float*)d_in[9];
  const float* g1       = (const float*)d_in[10];
  const float* beta1    = (const float*)d_in[11];
  const int*   bcols    = (const int*)d_in[12];
  float* outp = (float*)d_out;

  // ws: fbt [0,32MiB) (dead after L0); hB [0,64MiB); hA [64,128MiB).
  bf16* fbt = (bf16*)d_ws;                          // [BRQ][128][16]
  bf16* hB  = (bf16*)d_ws;                          // [BRQ][256][16]
  bf16* hA  = (bf16*)d_ws + (size_t)N_NODES * HID;  // [BRQ][256][16]

  // transposed bf16 weights in d_out scratch (d_out untouched until out-layer,
  // and the out-layer reads only W2 from d_in -> no race).
  bf16* w0t = (bf16*)d_out;         // [256][128]
  bf16* w1t = w0t + IN_F * HID;     // [256][256]

  transpose_all<<<dim3(384), dim3(256), 0, stream>>>(W0, W1, w0t, w1t);
  prep_fbt<<<dim3(BRQ), dim3(256), 0, stream>>>(features, fbt);

  // layer 0: hA = LN(relu((A@fbt) @ W0 + b0))
  fused_v2<IN_F, HID, false><<<dim3(BRQ / 8), dim3(512), 0, stream>>>(
      bvals, bcols, fbt, w0t, nullptr, b0v, g0, beta0, hA, nullptr);
  // layer 1: hB = LN(relu((A@hA) @ W1 + b1))
  fused_v2<HID, HID, false><<<dim3(BRQ / 8), dim3(512), 0, stream>>>(
      bvals, bcols, hA, w1t, nullptr, b1v, g1, beta1, hB, nullptr);
  // output layer: out = (A@hB) @ W2 + b2  (f32 row-major)
  fused_v2<HID, NCLS, true><<<dim3(BRQ / 8), dim3(512), 0, stream>>>(
      bvals, bcols, hB, nullptr, W2, b2v, nullptr, nullptr, nullptr, outp);
}

// Round 5
// 467.979 us; speedup vs baseline: 1.2612x; 1.2612x over previous
//
#include <hip/hip_runtime.h>
#include <hip/hip_bf16.h>

// GCN over Block-CSR adjacency. ALL I/O BUFFERS ARE FLOAT32 (reference dtypes).
// Compute: bf16 MFMA, fp32 accumulate; intermediates stored bf16.
//
// Round 11: champion gather schedule (R6, 3.8 TB/s) kept verbatim; cut BYTES.
// Evidence R7/R8/R10: every alternative schedule (reg-pipeline, LDS-DMA,
// batched-fused) lands at 1.7-3.5 TB/s; champion's simple high-occupancy
// kernel is the best gather engine. Changes:
//  - bf16 A-values (prep_bvals, identical numerics: MFMA ate bf16 anyway).
//    Ab lives in d_out (exactly 33.55 MB); spmm_out reads Ab[b] and overwrites
//    the same per-wave-private 4KB with out[b] -> race-free in-place.
//  - L0 reordered: S0 = A@fbt (128-wide gather = HALF the L0 gather bytes),
//    then gemm_ln0: h0 = LN(relu(S0@W0+b0)) with LN fused (4 waves share a
//    row-tile; 512B LDS exchange; lgkm-only barrier keeps aw prefetch alive).
//  - W matrices read f32-direct with strided frag build (R10 out-layer pattern,
//    proven): transpose_all deleted, d_out freed for Ab.
//  - L1 / OUT: champion kernels byte-identical except A-pointer type.
//
// ws (128 MiB): fbt@[0,32) -> h0@[0,64) -> h1@[0,64) ; S0@[64,96) ->
// zbt1@[64,128) -> zbt2@[64,80). All lifetimes disjoint.

typedef __bf16 bf16;
typedef bf16 bf16x8 __attribute__((ext_vector_type(8)));
typedef bf16 bf16x4 __attribute__((ext_vector_type(4)));
typedef float f32x4 __attribute__((ext_vector_type(4)));

#define N_NODES 131072
#define BRQ 8192      // block rows (= N/16)
#define KNZ 8         // nonzero blocks per block row
#define IN_F 128
#define HID 256
#define NCLS 64

#define SB() __builtin_amdgcn_sched_barrier(0)

static __device__ __forceinline__ f32x4 mfma16(bf16x8 a, bf16x8 b, f32x4 c) {
  return __builtin_amdgcn_mfma_f32_16x16x32_bf16(a, b, c, 0, 0, 0);
}

static __device__ __forceinline__ bf16x8 load8(const bf16* p) {
  return *(const bf16x8*)p;
}
static __device__ __forceinline__ bf16x8 cvt8(f32x4 a0, f32x4 a1) {
  bf16x8 r;
  r[0] = (bf16)a0[0]; r[1] = (bf16)a0[1]; r[2] = (bf16)a0[2]; r[3] = (bf16)a0[3];
  r[4] = (bf16)a1[0]; r[5] = (bf16)a1[1]; r[6] = (bf16)a1[2]; r[7] = (bf16)a1[3];
  return r;
}

// ---------------- A block-values f32 -> bf16 (identical numerics) ----------------
__global__ __launch_bounds__(256) void prep_bvals(const float* __restrict__ V,
                                                  bf16* __restrict__ Ab) {
  long i = ((long)blockIdx.x * 256 + threadIdx.x) * 8;
  f32x4 a0 = *(const f32x4*)(V + i);
  f32x4 a1 = *(const f32x4*)(V + i + 4);
  *(bf16x8*)(Ab + i) = cvt8(a0, a1);
}

// ---------------- features -> blocked-transposed bf16 [BRQ][128][16] -------------
__global__ __launch_bounds__(256) void prep_fbt(const float* __restrict__ F,
                                                bf16* __restrict__ out) {
  __shared__ float T[16][132];
  const int b = blockIdx.x, tid = threadIdx.x;
#pragma unroll
  for (int p = 0; p < 2; ++p) {
    int ci = tid + p * 256;            // f32x4 chunk id (512 total)
    int r = ci >> 5, c4 = ci & 31;
    f32x4 v = *(const f32x4*)(F + ((long)b * 16 + r) * 128 + c4 * 4);
    *(f32x4*)&T[r][c4 * 4] = v;
  }
  __syncthreads();
  int f = tid >> 1, r0 = (tid & 1) * 8;
  bf16x8 o;
#pragma unroll
  for (int e = 0; e < 8; ++e) o[e] = (bf16)T[r0 + e][f];
  *(bf16x8*)(out + (long)b * 2048 + f * 16 + r0) = o;
}

// ---------------- S0 = A @ fbt (F = 128, no LN) — champion gather structure ------
__global__ __launch_bounds__(256) void spmm_f(const bf16* __restrict__ Ab,
                                              const int*  __restrict__ Abc,
                                              const bf16* __restrict__ Fbt,
                                              bf16* __restrict__ S0) {
  const int wave = threadIdx.x >> 6;
  const int b    = blockIdx.x * 4 + wave;   // one block-row per wave
  const int lane = threadIdx.x & 63;
  const int l15  = lane & 15;
  const int quad = lane >> 4;
  const int cst  = (quad & 1) * 8;
  const int half = quad >> 1;

  const int*  bc    = Abc + b * KNZ;
  const bf16* abase = Ab + (long)b * (KNZ * 256) + l15 * 16 + cst;

  bf16x8 afr[4];
  long   zb[4];
#pragma unroll
  for (int kp = 0; kp < 4; ++kp) {
    int blk = 2 * kp + half;
    afr[kp] = load8(abase + blk * 256);
    zb[kp]  = (long)bc[blk] * (IN_F * 16) + cst;
  }
  bf16x8 bfr[4][8];
#pragma unroll
  for (int kp = 0; kp < 4; ++kp)
#pragma unroll
    for (int t = 0; t < 8; ++t) {
      int f = t * 16 + l15;
      bfr[kp][t] = *(const bf16x8*)(Fbt + zb[kp] + f * 16);
    }

  f32x4 acc[8] = {};
#pragma unroll
  for (int kp = 0; kp < 4; ++kp)
#pragma unroll
    for (int t = 0; t < 8; ++t)
      acc[t] = mfma16(afr[kp], bfr[kp][t], acc[t]);

#pragma unroll
  for (int t = 0; t < 8; ++t)
#pragma unroll
    for (int i = 0; i < 4; ++i)
      S0[((long)b * 16 + quad * 4 + i) * IN_F + t * 16 + l15] = (bf16)acc[t][i];
}

// ---------------- dense GEMM, B-stationary, W f32-direct; optional fused LN ------
// X row-major bf16 [N][KIN]. LN=true: out = LN(relu(X@W + bias)) row-major bf16.
// LN=false: out = X@W in blocked-transposed zbt layout [BRQ][FOUT][16].
template<int KIN, int FOUT, int GRID, bool LN>
__global__ __launch_bounds__(256) void gemm_ln(const bf16*  __restrict__ X,
                                               const float* __restrict__ W,
                                               const float* __restrict__ bias,
                                               const float* __restrict__ gamma,
                                               const float* __restrict__ beta,
                                               bf16* __restrict__ Hrow,
                                               bf16* __restrict__ Zbt) {
  constexpr int CG  = FOUT / 64;          // 64-col groups
  constexpr int KS  = KIN / 32;           // K steps
  constexpr int RTS = GRID * 4 / CG;      // row-tile stride (waves per col group)
  constexpr int NT  = BRQ / RTS;          // row-tiles per wave

  const int wave = threadIdx.x >> 6;
  const int lane = threadIdx.x & 63;
  const int l15  = lane & 15;
  const int quad = lane >> 4;
  const int gw   = blockIdx.x * 4 + wave;
  const int cg   = gw % CG;               // CG=4: cg == wave -> WG shares row-tile
  const int rt0  = gw / CG;

  // B-frags built from f32 W [KIN][FOUT] with strided loads (L2-resident).
  bf16x8 wbf[KS][4];
#pragma unroll
  for (int k = 0; k < KS; ++k)
#pragma unroll
    for (int t = 0; t < 4; ++t) {
      const float* wp = W + (long)(k * 32 + quad * 8) * FOUT + cg * 64 + t * 16 + l15;
      bf16x8 v;
#pragma unroll
      for (int j = 0; j < 8; ++j) v[j] = (bf16)wp[(long)j * FOUT];
      wbf[k][t] = v;
    }
  float bv[4], gv[4], btv[4];
  if constexpr (LN) {
#pragma unroll
    for (int t = 0; t < 4; ++t) {
      int col = cg * 64 + t * 16 + l15;
      bv[t] = bias[col]; gv[t] = gamma[col]; btv[t] = beta[col];
    }
  }

  __shared__ float S[2][4][16], SS[2][4][16];   // LN cross-wave exchange (parity)

  const bf16* __restrict__ xbase = X + (long)l15 * KIN + quad * 8;

  bf16x8 aw[2][KS];
#pragma unroll
  for (int k = 0; k < KS; ++k)
    aw[0][k] = load8(xbase + (long)rt0 * (16 * KIN) + k * 32);

#pragma unroll
  for (int it = 0; it < NT; ++it) {
    const int rt = rt0 + it * RTS;
    if (it + 1 < NT) {
      const long xoff = (long)(rt + RTS) * (16 * KIN);
#pragma unroll
      for (int k = 0; k < KS; ++k)
        aw[(it + 1) & 1][k] = load8(xbase + xoff + k * 32);
    }
    f32x4 acc[4] = {};
#pragma unroll
    for (int k = 0; k < KS; ++k)
#pragma unroll
      for (int t = 0; t < 4; ++t)
        acc[t] = mfma16(aw[it & 1][k], wbf[k][t], acc[t]);

    if constexpr (LN) {
      // bias + relu + per-row partial sums over this wave's 64 cols
      float ps[4] = {0.f, 0.f, 0.f, 0.f}, pss[4] = {0.f, 0.f, 0.f, 0.f};
#pragma unroll
      for (int t = 0; t < 4; ++t)
#pragma unroll
        for (int i = 0; i < 4; ++i) {
          float v = acc[t][i] + bv[t];
          v = v > 0.f ? v : 0.f;
          acc[t][i] = v;
          ps[i] += v;
          pss[i] += v * v;
        }
#pragma unroll
      for (int m = 1; m < 16; m <<= 1)
#pragma unroll
        for (int i = 0; i < 4; ++i) {
          ps[i]  += __shfl_xor(ps[i], m, 64);
          pss[i] += __shfl_xor(pss[i], m, 64);
        }
      const int par = it & 1;
      if (l15 == 0)
#pragma unroll
        for (int i = 0; i < 4; ++i) {
          S[par][wave][quad * 4 + i]  = ps[i];
          SS[par][wave][quad * 4 + i] = pss[i];
        }
      // raw barrier: drain LDS only; aw prefetch (vm) stays in flight.
      SB();
      asm volatile("s_waitcnt lgkmcnt(0)" ::: "memory");
      __builtin_amdgcn_s_barrier();
      SB();
#pragma unroll
      for (int i = 0; i < 4; ++i) {
        int r = quad * 4 + i;
        float s  = S[par][0][r] + S[par][1][r] + S[par][2][r] + S[par][3][r];
        float ss = SS[par][0][r] + SS[par][1][r] + SS[par][2][r] + SS[par][3][r];
        float mu   = s * (1.f / FOUT);
        float var  = ss * (1.f / FOUT) - mu * mu;
        float rstd = rsqrtf(var + 1e-5f);
        bf16* hrow = Hrow + ((long)rt * 16 + r) * FOUT + cg * 64;
#pragma unroll
        for (int t = 0; t < 4; ++t)
          hrow[t * 16 + l15] = (bf16)((acc[t][i] - mu) * rstd * gv[t] + btv[t]);
      }
    } else {
#pragma unroll
      for (int t = 0; t < 4; ++t) {
        int col = cg * 64 + t * 16 + l15;
        bf16x4 v;
#pragma unroll
        for (int i = 0; i < 4; ++i) v[i] = (bf16)acc[t][i];
        *(bf16x4*)(Zbt + ((long)rt * FOUT + col) * 16 + quad * 4) = v;
      }
    }
  }
}

// ---------------- SpMM + bias + ReLU + LayerNorm (F = HID = 256) — CHAMPION ------
// Byte-identical to the R6 93.5us kernel except A is bf16.
__global__ __launch_bounds__(256) void spmm_ln(const bf16*  __restrict__ Abv,
                                               const int*   __restrict__ Abc,
                                               const bf16*  __restrict__ Zbt,
                                               const float* __restrict__ bias,
                                               const float* __restrict__ gamma,
                                               const float* __restrict__ beta,
                                               bf16* __restrict__ H) {
  const int wave = threadIdx.x >> 6;
  const int lane = threadIdx.x & 63;
  const int l15  = lane & 15;
  const int quad = lane >> 4;
  const int b    = blockIdx.x * 2 + (wave >> 1);
  const int ch   = wave & 1;               // column half

  const int*  bc    = Abc + b * KNZ;
  const int   cst   = (quad & 1) * 8;
  const int   half  = quad >> 1;
  const bf16* abase = Abv + (long)b * (KNZ * 256) + l15 * 16 + cst;

  bf16x8 afr[4];
  long   zb[4];
#pragma unroll
  for (int kp = 0; kp < 4; ++kp) {
    int blk = 2 * kp + half;
    afr[kp] = load8(abase + blk * 256);
    zb[kp]  = (long)bc[blk] * (HID * 16) + cst;
  }
  bf16x8 bfr[4][8];
#pragma unroll
  for (int kp = 0; kp < 4; ++kp)
#pragma unroll
    for (int t = 0; t < 8; ++t) {
      int f = ch * 128 + t * 16 + l15;
      bfr[kp][t] = *(const bf16x8*)(Zbt + zb[kp] + f * 16);
    }

  f32x4 acc[8] = {};
#pragma unroll
  for (int kp = 0; kp < 4; ++kp)
#pragma unroll
    for (int t = 0; t < 8; ++t)
      acc[t] = mfma16(afr[kp], bfr[kp][t], acc[t]);

  // bias + relu in-register, accumulate per-row partial sums
  float gv[8], bv[8];
#pragma unroll
  for (int t = 0; t < 8; ++t) {
    int f = ch * 128 + t * 16 + l15;
    gv[t] = gamma[f];
    bv[t] = beta[f];
  }
  float ps[4] = {0.f, 0.f, 0.f, 0.f}, pss[4] = {0.f, 0.f, 0.f, 0.f};
#pragma unroll
  for (int t = 0; t < 8; ++t) {
    float bi = bias[ch * 128 + t * 16 + l15];
#pragma unroll
    for (int i = 0; i < 4; ++i) {
      float v = acc[t][i] + bi;
      v = v > 0.f ? v : 0.f;
      acc[t][i] = v;
      ps[i] += v;
      pss[i] += v * v;
    }
  }
#pragma unroll
  for (int m = 1; m < 16; m <<= 1) {
#pragma unroll
    for (int i = 0; i < 4; ++i) {
      ps[i]  += __shfl_xor(ps[i], m, 64);
      pss[i] += __shfl_xor(pss[i], m, 64);
    }
  }
  __shared__ float S[4][16], SS[4][16];
  if (l15 == 0) {
#pragma unroll
    for (int i = 0; i < 4; ++i) {
      S[wave][quad * 4 + i]  = ps[i];
      SS[wave][quad * 4 + i] = pss[i];
    }
  }
  __syncthreads();
#pragma unroll
  for (int i = 0; i < 4; ++i) {
    int r = quad * 4 + i;
    float s    = S[wave][r] + S[wave ^ 1][r];
    float ss   = SS[wave][r] + SS[wave ^ 1][r];
    float mu   = s * (1.f / 256.f);
    float var  = ss * (1.f / 256.f) - mu * mu;
    float rstd = rsqrtf(var + 1e-5f);
    bf16* hrow = H + (long)(b * 16 + r) * HID;
#pragma unroll
    for (int t = 0; t < 8; ++t) {
      int f = ch * 128 + t * 16 + l15;
      float y = (acc[t][i] - mu) * rstd * gv[t] + bv[t];
      hrow[f] = (bf16)y;
    }
  }
}

// ---------------- final SpMM + bias (F = NCLS = 64), f32 out — CHAMPION ----------
// A is bf16 and lives in d_out; each wave reads its private 4KB then overwrites
// the exact same 4KB with its f32 output rows (read -> acc -> store, race-free).
__global__ __launch_bounds__(256) void spmm_out(const bf16*  __restrict__ Abv,
                                                const int*   __restrict__ Abc,
                                                const bf16*  __restrict__ Zbt,  // [BRQ,64,16]
                                                const float* __restrict__ bias, // [64]
                                                float* __restrict__ out) {      // [N,64] f32
  const int wave = threadIdx.x >> 6;
  const int b    = blockIdx.x * 4 + wave;   // one block-row per wave
  const int lane = threadIdx.x & 63;
  const int l15  = lane & 15;
  const int quad = lane >> 4;

  const int*  bc    = Abc + b * KNZ;
  const int   cst   = (quad & 1) * 8;
  const int   half  = quad >> 1;
  const bf16* abase = Abv + (long)b * (KNZ * 256) + l15 * 16 + cst;

  bf16x8 afr[4];
  long   zb[4];
#pragma unroll
  for (int kp = 0; kp < 4; ++kp) {
    int blk = 2 * kp + half;
    afr[kp] = load8(abase + blk * 256);
    zb[kp]  = (long)bc[blk] * (NCLS * 16) + cst;
  }
  bf16x8 bfr[4][4];
#pragma unroll
  for (int kp = 0; kp < 4; ++kp)
#pragma unroll
    for (int t = 0; t < 4; ++t) {
      int f = t * 16 + l15;
      bfr[kp][t] = *(const bf16x8*)(Zbt + zb[kp] + f * 16);
    }

  f32x4 acc[4] = {};
#pragma unroll
  for (int kp = 0; kp < 4; ++kp)
#pragma unroll
    for (int t = 0; t < 4; ++t)
      acc[t] = mfma16(afr[kp], bfr[kp][t], acc[t]);

#pragma unroll
  for (int t = 0; t < 4; ++t) {
    int f = t * 16 + l15;
    float bi = bias[f];
#pragma unroll
    for (int i = 0; i < 4; ++i) {
      out[(long)(b * 16 + quad * 4 + i) * NCLS + f] = acc[t][i] + bi;
    }
  }
}

extern "C" void kernel_launch(void* const* d_in, const int* in_sizes, int n_in,
                              void* d_out, int out_size, void* d_ws, size_t ws_size,
                              hipStream_t stream) {
  const float* features = (const float*)d_in[0];
  const float* bvals    = (const float*)d_in[1];
  const float* W0       = (const float*)d_in[2];
  const float* b0v      = (const float*)d_in[3];
  const float* W1       = (const float*)d_in[4];
  const float* b1v      = (const float*)d_in[5];
  const float* W2       = (const float*)d_in[6];
  const float* b2v      = (const float*)d_in[7];
  const float* g0       = (const float*)d_in[8];
  const float* beta0    = (const float*)d_in[9];
  const float* g1       = (const float*)d_in[10];
  const float* beta1    = (const float*)d_in[11];
  const int*   bcols    = (const int*)d_in[12];
  float* outp = (float*)d_out;

  // ws (128 MiB), disjoint lifetimes:
  char* ws = (char*)d_ws;
  bf16* fbt  = (bf16*)ws;                    // [0,32MiB)   prep_fbt -> spmm_f
  bf16* S0   = (bf16*)(ws + (64L << 20));    // [64,96)     spmm_f   -> gemm_ln0
  bf16* h0   = (bf16*)ws;                    // [0,64)      gemm_ln0 -> gemm1 (over dead fbt)
  bf16* zbt1 = (bf16*)(ws + (64L << 20));    // [64,128)    gemm1    -> spmm_ln (over dead S0)
  bf16* h1   = (bf16*)ws;                    // [0,64)      spmm_ln  -> gemm2 (over dead h0)
  bf16* zbt2 = (bf16*)(ws + (64L << 20));    // [64,80)     gemm2    -> spmm_out (over dead zbt1)

  // bf16 A-values fill d_out exactly (33,554,432 B); spmm_out overwrites in place.
  bf16* Ab = (bf16*)d_out;

  prep_bvals<<<dim3(BRQ), dim3(256), 0, stream>>>(bvals, Ab);
  prep_fbt<<<dim3(BRQ), dim3(256), 0, stream>>>(features, fbt);

  // L0: S0 = A@fbt (128-wide gather), then h0 = LN(relu(S0@W0 + b0))
  spmm_f<<<dim3(BRQ / 4), dim3(256), 0, stream>>>(Ab, bcols, fbt, S0);
  gemm_ln<IN_F, HID, 1024, true><<<dim3(1024), dim3(256), 0, stream>>>(
      S0, W0, b0v, g0, beta0, h0, nullptr);
  // L1: zbt1 = h0@W1, then h1 = LN(relu(A@zbt1 + b1))  (champion path)
  gemm_ln<HID, HID, 1024, false><<<dim3(1024), dim3(256), 0, stream>>>(
      h0, W1, nullptr, nullptr, nullptr, nullptr, zbt1);
  spmm_ln<<<dim3(BRQ / 2), dim3(256), 0, stream>>>(Ab, bcols, zbt1, b1v, g1, beta1, h1);
  // OUT: zbt2 = h1@W2, then out = A@zbt2 + b2  (champion path, in-place over Ab)
  gemm_ln<HID, NCLS, 512, false><<<dim3(512), dim3(256), 0, stream>>>(
      h1, W2, nullptr, nullptr, nullptr, nullptr, zbt2);
  spmm_out<<<dim3(BRQ / 4), dim3(256), 0, stream>>>(Ab, bcols, zbt2, b2v, outp);
}